// Round 1
// baseline (2722.305 us; speedup 1.0000x reference)
//
#include <hip/hip_runtime.h>
#include <math.h>

#define N_MEM 100
#define C_DIM 768
#define HW_SZ 2304            // 48*48
#define TEMP 0.07f
#define EPS_F 1e-8f
#define LAM_F 0.01f           // 1/N_MEM
#define NORM_EPS 1e-12f

// -------------------------------------------------------------------------
// Kernel 1: L2-normalize each memory row and store TRANSPOSED: mT[c][n].
// Transposed layout makes the main kernel's per-c access a contiguous,
// wave-uniform 100-float row -> compiler emits scalar loads (s_load).
// -------------------------------------------------------------------------
__global__ __launch_bounds__(64) void prep_mT(const float* __restrict__ mem,
                                              float* __restrict__ mT) {
    const int n = blockIdx.x;        // 0..99  (one wave per memory row)
    const int lane = threadIdx.x;    // 0..63
    const float* row = mem + n * C_DIM;

    float ss = 0.f;
    for (int c = lane; c < C_DIM; c += 64) {
        float v = row[c];
        ss = fmaf(v, v, ss);
    }
    // full-wave butterfly reduce (wave = 64 on CDNA)
    for (int off = 32; off > 0; off >>= 1)
        ss += __shfl_down(ss, off);
    float norm = sqrtf(__shfl(ss, 0));
    float inv = 1.0f / fmaxf(norm, NORM_EPS);

    for (int c = lane; c < C_DIM; c += 64)
        mT[c * N_MEM + n] = row[c] * inv;
}

// -------------------------------------------------------------------------
// Kernel 2: fused  scores -> softmax -> shrinkage -> renorm -> reconstruct.
// One thread per spatial row (b, hw). 100 fp32 accumulators in VGPRs.
// F is read exactly once; z-norm is folded into a post-scale of the dot.
// -------------------------------------------------------------------------
__global__ __launch_bounds__(64) void memmod_main(const float* __restrict__ F,
                                                  const float* __restrict__ mT,
                                                  float* __restrict__ Fhat,
                                                  float* __restrict__ What) {
    const int blk = blockIdx.x;                    // 0..2303
    const int b   = blk / 36;                      // 2304/64 = 36 blocks per image
    const int hw  = (blk % 36) * 64 + threadIdx.x; // 0..2303
    const size_t plane = (size_t)b * C_DIM * HW_SZ + hw;

    float acc[N_MEM];
#pragma unroll
    for (int n = 0; n < N_MEM; ++n) acc[n] = 0.f;
    float ss = 0.f;

    // ---- scores GEMM: acc[n] = sum_c z[c] * m_norm[n][c];  ss = |z|^2 ----
    const float* Fp = F + plane;
    for (int c = 0; c < C_DIM; ++c) {
        const float zc = Fp[(size_t)c * HW_SZ];        // coalesced across lanes
        ss = fmaf(zc, zc, ss);
        const float* mrow = mT + c * N_MEM;            // wave-uniform address
#pragma unroll
        for (int n = 0; n < N_MEM; ++n)
            acc[n] = fmaf(zc, mrow[n], acc[n]);
    }

    // ---- scale by 1/(||z|| * T), softmax (max-subtracted, like jax) ----
    const float scale = 1.0f / (fmaxf(sqrtf(ss), NORM_EPS) * TEMP);
    float mx = -INFINITY;
#pragma unroll
    for (int n = 0; n < N_MEM; ++n) {
        acc[n] *= scale;
        mx = fmaxf(mx, acc[n]);
    }
    float sum = 0.f;
#pragma unroll
    for (int n = 0; n < N_MEM; ++n) {
        acc[n] = expf(acc[n] - mx);
        sum += acc[n];
    }
    // real IEEE divisions: keep w bit-close to reference (shrinkage boundary!)
    float s2 = 0.f;
#pragma unroll
    for (int n = 0; n < N_MEM; ++n) {
        const float w = acc[n] / sum;
        const float d = w - LAM_F;
        const float wh = (d > 0.f ? d : 0.f) * w / (fabsf(d) + EPS_F);
        acc[n] = wh;
        s2 += wh;
    }
    const float s2c = fmaxf(s2, EPS_F);
#pragma unroll
    for (int n = 0; n < N_MEM; ++n)
        acc[n] = acc[n] / s2c;

    // ---- emit w_hat_spatial [b][p][n]: 25 x float4 stores (16B aligned) ----
    float* wout = What + (size_t)(b * HW_SZ + hw) * N_MEM;
#pragma unroll
    for (int n = 0; n < N_MEM; n += 4) {
        float4 v = make_float4(acc[n], acc[n + 1], acc[n + 2], acc[n + 3]);
        *reinterpret_cast<float4*>(wout + n) = v;
    }

    // ---- reconstruction GEMM: Fhat[b][c][hw] = sum_n w_hat[n] * m[n][c] ----
    float* Fo = Fhat + plane;
    for (int c = 0; c < C_DIM; ++c) {
        const float* mrow = mT + c * N_MEM;            // wave-uniform address
        float v = 0.f;
#pragma unroll
        for (int n = 0; n < N_MEM; ++n)
            v = fmaf(acc[n], mrow[n], v);
        Fo[(size_t)c * HW_SZ] = v;                     // coalesced across lanes
    }
}

// -------------------------------------------------------------------------
extern "C" void kernel_launch(void* const* d_in, const int* in_sizes, int n_in,
                              void* d_out, int out_size, void* d_ws, size_t ws_size,
                              hipStream_t stream) {
    const float* F   = (const float*)d_in[0];   // [64,768,48,48]
    const float* mem = (const float*)d_in[1];   // [100,768]
    float* Fhat = (float*)d_out;                               // 113,246,208 floats
    float* What = (float*)d_out + (size_t)64 * 768 * 48 * 48;  // 14,745,600 floats
    float* mT   = (float*)d_ws;                                // 76,800 floats

    prep_mT<<<N_MEM, 64, 0, stream>>>(mem, mT);
    memmod_main<<<(64 * HW_SZ) / 64, 64, 0, stream>>>(F, mT, Fhat, What);
}